// Round 5
// baseline (297.772 us; speedup 1.0000x reference)
//
#include <hip/hip_runtime.h>
#include <math.h>

// Problem constants (from reference)
constexpr int kB = 256, kT = 8, kS = 200, kR = 8, kD = 64, kF = 20;

// ---------------------------------------------------------------------------
// One block per (b,t), 256 threads = 4 waves, grid 2048.
// Block mapping: b = o%256, t = o/256  ->  o%8 == b%8, so all 8 t-blocks of a
// given b dispatch to the SAME XCD (o%8 round-robin): seq[b] (51 KB) is HBM-
// fetched once and L2-served 7x. Per-XCD seq footprint = 32 b's = 1.6MB < 4MB.
//
//   P0 : stage fr/fi transposed -> LDS; ri[r][d] = (rel+tv)*target -> LDS
//   P1 : thread s (<200): dec[r][s] via 20x __sincosf (k-outer, r-inner b128)
//        and att[r][s] = seq[b,s,:].ri[r,:]  (valid ? . : -inf)
//   P2 : wave w: softmax rows r=2w,2w+1 over s (shfl reduce), in place:
//        att[r][s] = e/denom * dec[r][s]
//   P3 : wave w owns s-groups g===w (mod 4), g=[4g,4g+4): acc[r] += seq*att
//        (8x b128 broadcast along s), partials -> LDS
//   P4 : cross-wave reduce, coalesced store
// NOTES:
//  - global `att - att.max()` is shift-invariant under softmax -> omitted.
//  - decay concat halves identical: mean(2F)/2 == sum_F/(2F)  (== acc/40).
//  - d_ws deliberately unused: harness poison-fill of ws costs ~43us serial.
// ---------------------------------------------------------------------------
__global__ __launch_bounds__(256, 8) void rda_fused(
    const float* __restrict__ seq,    // [B,S,D]
    const float* __restrict__ dt,     // [B,S]
    const float* __restrict__ target, // [B,T,D]
    const float* __restrict__ tv,     // [B,T,R,D]
    const int*   __restrict__ vm,     // [B,S]
    const float* __restrict__ rel,    // [R,D]
    const float* __restrict__ fr,     // [R,F]
    const float* __restrict__ fi,     // [R,F]
    float* __restrict__ out)          // [B,T,R,D]
{
    __shared__ float ri[kR * kD];        // 2 KB
    __shared__ float att[kR][kS];        // 6.4 KB, stride-1 rows (conflict-free)
    // union (time-disjoint, barrier-fenced):
    //   P1/P2: dec = u[0..1599] ([r][s]), ffT = u[1600..2239] (frT then fiT, [k][r])
    //   P3/P4: part = u[0..2047] ([w][r][d])
    __shared__ float u[2240];            // 8.96 KB

    const int o = blockIdx.x;
    const int b = o & 255, t = o >> 8;
    const int bt = b * kT + t;
    const int tid = threadIdx.x, wave = tid >> 6, lane = tid & 63;

    float* dec = u;                       // [r*200+s]
    float* frT = u + 1600;                // [k*8+r]
    float* fiT = u + 1760;                // [k*8+r]
    float* part = u;                      // [(w*8+r)*64+d]

    // ---- P0: stage transposed fr/fi and ri
    if (tid < 2 * kR * kF) {              // first 256 of 320 entries
        int idx = tid;
        int tab = idx >= kR * kF; int j = idx - tab * kR * kF;
        u[1600 + idx] = (tab ? fi : fr)[(j & 7) * kF + (j >> 3)];
    }
    if (tid < 2 * kR * kF - 256) {        // remaining 64
        int idx = tid + 256;
        int j = idx - kR * kF;            // all in fi half
        u[1600 + idx] = fi[(j & 7) * kF + (j >> 3)];
    }
    {
        const float* tvb = tv + (size_t)bt * kR * kD;
        const float* tgb = target + (size_t)bt * kD;
        for (int idx = tid; idx < kR * kD; idx += 256)
            ri[idx] = (rel[idx] + tvb[idx]) * tgb[idx & 63];
    }
    __syncthreads();

    // ---- P1: decay + raw scores (thread = s)
    if (tid < kS) {
        const int s = tid;
        const bool valid = vm[b * kS + s] != 0;

        // decay: k-outer, 8 r-accumulators, transposed b128 broadcast reads
        {
            const float tt = dt[b * kS + s];
            float acc[kR];
#pragma unroll
            for (int r = 0; r < kR; ++r) acc[r] = 0.f;
#pragma unroll
            for (int k = 0; k < kF; ++k) {
                float w = 6.283185307179586f * ((float)k * (0.5f / (kF - 1))) * tt;
                float sn, cs; __sincosf(w, &sn, &cs);
                float4 f0 = *(const float4*)&frT[k * 8];
                float4 f1 = *(const float4*)&frT[k * 8 + 4];
                float4 g0 = *(const float4*)&fiT[k * 8];
                float4 g1 = *(const float4*)&fiT[k * 8 + 4];
                acc[0] += cs * f0.x - sn * g0.x;  acc[1] += cs * f0.y - sn * g0.y;
                acc[2] += cs * f0.z - sn * g0.z;  acc[3] += cs * f0.w - sn * g0.w;
                acc[4] += cs * f1.x - sn * g1.x;  acc[5] += cs * f1.y - sn * g1.y;
                acc[6] += cs * f1.z - sn * g1.z;  acc[7] += cs * f1.w - sn * g1.w;
            }
#pragma unroll
            for (int r = 0; r < kR; ++r) {
                float v = fminf(fmaxf(acc[r] * (1.0f / (2.0f * kF)), 0.f), 1.f);
                dec[r * kS + s] = valid ? v : 0.f;
            }
        }

        // raw scores
        {
            const float4* seqrow = (const float4*)(seq + (size_t)(b * kS + s) * kD);
            float a[kR];
#pragma unroll
            for (int r = 0; r < kR; ++r) a[r] = 0.f;
#pragma unroll
            for (int uu = 0; uu < kD / 4; ++uu) {
                float4 sv = seqrow[uu];
#pragma unroll
                for (int r = 0; r < kR; ++r) {
                    float4 rv = ((const float4*)(ri + r * kD))[uu];
                    a[r] += sv.x * rv.x + sv.y * rv.y + sv.z * rv.z + sv.w * rv.w;
                }
            }
#pragma unroll
            for (int r = 0; r < kR; ++r)
                att[r][s] = valid ? a[r] : -INFINITY;
        }
    }
    __syncthreads();

    // ---- P2: masked softmax * decay (wave w -> rows 2w, 2w+1)
#pragma unroll
    for (int h = 0; h < 2; ++h) {
        const int r = 2 * wave + h;
        float* row = &att[r][0];
        float a0 = row[lane];
        float a1 = row[lane + 64];
        float a2 = row[lane + 128];
        float a3 = (lane < kS - 192) ? row[lane + 192] : -INFINITY;
        float m = fmaxf(fmaxf(a0, a1), fmaxf(a2, a3));
#pragma unroll
        for (int off = 32; off; off >>= 1) m = fmaxf(m, __shfl_xor(m, off));
        float e0 = __expf(a0 - m), e1 = __expf(a1 - m), e2 = __expf(a2 - m);
        float e3 = (lane < kS - 192) ? __expf(a3 - m) : 0.f;
        float ssum = e0 + e1 + e2 + e3;
#pragma unroll
        for (int off = 32; off; off >>= 1) ssum += __shfl_xor(ssum, off);
        const float inv = 1.0f / ssum;
        row[lane]       = e0 * inv * dec[r * kS + lane];
        row[lane + 64]  = e1 * inv * dec[r * kS + lane + 64];
        row[lane + 128] = e2 * inv * dec[r * kS + lane + 128];
        if (lane < kS - 192)
            row[lane + 192] = e3 * inv * dec[r * kS + lane + 192];
    }
    __syncthreads();   // P3 reads all att rows; also fences dec -> part union

    // ---- P3: context partials; wave w takes s-groups g === w (mod 4)
    {
        float acc[kR];
#pragma unroll
        for (int r = 0; r < kR; ++r) acc[r] = 0.f;
        const float* seqb = seq + (size_t)b * kS * kD + lane;
        for (int g = wave; g < kS / 4; g += 4) {
            const int s0 = 4 * g;
            float4 av[kR];
#pragma unroll
            for (int r = 0; r < kR; ++r)
                av[r] = *(const float4*)&att[r][s0];
            float sv0 = seqb[(size_t)(s0 + 0) * kD];
            float sv1 = seqb[(size_t)(s0 + 1) * kD];
            float sv2 = seqb[(size_t)(s0 + 2) * kD];
            float sv3 = seqb[(size_t)(s0 + 3) * kD];
#pragma unroll
            for (int r = 0; r < kR; ++r)
                acc[r] += sv0 * av[r].x + sv1 * av[r].y + sv2 * av[r].z + sv3 * av[r].w;
        }
#pragma unroll
        for (int r = 0; r < kR; ++r)
            part[(wave * kR + r) * kD + lane] = acc[r];
    }
    __syncthreads();

    // ---- P4: reduce partials, coalesced store
    {
        int idx = tid;
#pragma unroll
        for (int it = 0; it < 2; ++it, idx += 256) {
            float v = part[idx] + part[512 + idx] + part[1024 + idx] + part[1536 + idx];
            out[(size_t)bt * kR * kD + idx] = v;
        }
    }
}

extern "C" void kernel_launch(void* const* d_in, const int* in_sizes, int n_in,
                              void* d_out, int out_size, void* d_ws, size_t ws_size,
                              hipStream_t stream) {
    const float* seq    = (const float*)d_in[0];
    const float* dt     = (const float*)d_in[1];
    const float* target = (const float*)d_in[2];
    const float* tv     = (const float*)d_in[3];
    const int*   vm     = (const int*)  d_in[4];
    const float* rel    = (const float*)d_in[5];
    const float* fr     = (const float*)d_in[6];
    const float* fi     = (const float*)d_in[7];
    float* out = (float*)d_out;

    rda_fused<<<kB * kT, 256, 0, stream>>>(seq, dt, target, tv, vm, rel, fr, fi, out);
}

// Round 6
// 131.971 us; speedup vs baseline: 2.2563x; 2.2563x over previous
//
#include <hip/hip_runtime.h>
#include <math.h>

// Problem constants (from reference)
constexpr int kB = 256, kT = 8, kS = 200, kR = 8, kD = 64, kF = 20;

// ---------------------------------------------------------------------------
// One block per (b,t), 256 threads = 4 waves, grid 2048.
// Block mapping: b = o%256, t = o/256  ->  o%8 == b%8, so all 8 t-blocks of a
// given b dispatch to the SAME XCD (o%8 round-robin): seq[b] (51 KB) is HBM-
// fetched once and L2-served 7x. Per-XCD seq footprint = 32 b's = 1.6MB < 4MB.
//
//   P0 : stage fr/fi transposed -> LDS; ri[r][d] = (rel+tv)*target -> LDS
//   P1 : thread s (<200): dec[r][s] via 20x __sincosf (k-outer, r-inner b128)
//        and att[r][s] = seq[b,s,:].ri[r,:]  (valid ? . : -inf)
//   P2 : wave w: softmax rows r=2w,2w+1 over s (shfl reduce), in place:
//        att[r][s] = e/denom * dec[r][s]
//   P3 : wave w owns s-groups g===w (mod 4): acc[r] += seq*att
//        (b128 broadcast along s), partials -> LDS
//   P4 : cross-wave reduce, coalesced store
// NOTES:
//  - global `att - att.max()` is shift-invariant under softmax -> omitted.
//  - decay concat halves identical: mean(2F)/2 == sum_F/(2F)  (== acc/40).
//  - d_ws deliberately unused: harness poison-fill of ws costs ~43us serial.
//  - __launch_bounds__(256,4): R5's (256,8) forced VGPR=32 -> 655 MB of
//    scratch spill traffic per launch, 237us. (256,4) caps at 128 VGPR:
//    no spill, still 16 waves/CU.
// ---------------------------------------------------------------------------
__global__ __launch_bounds__(256, 4) void rda_fused(
    const float* __restrict__ seq,    // [B,S,D]
    const float* __restrict__ dt,     // [B,S]
    const float* __restrict__ target, // [B,T,D]
    const float* __restrict__ tv,     // [B,T,R,D]
    const int*   __restrict__ vm,     // [B,S]
    const float* __restrict__ rel,    // [R,D]
    const float* __restrict__ fr,     // [R,F]
    const float* __restrict__ fi,     // [R,F]
    float* __restrict__ out)          // [B,T,R,D]
{
    __shared__ float ri[kR * kD];        // 2 KB
    __shared__ float att[kR][kS];        // 6.4 KB, stride-1 rows (conflict-free)
    // union (time-disjoint, barrier-fenced):
    //   P1/P2: dec = u[0..1599] ([r][s]), ffT = u[1600..2239] (frT then fiT, [k][r])
    //   P3/P4: part = u[0..2047] ([w][r][d])
    __shared__ float u[2240];            // 8.96 KB

    const int o = blockIdx.x;
    const int b = o & 255, t = o >> 8;
    const int bt = b * kT + t;
    const int tid = threadIdx.x, wave = tid >> 6, lane = tid & 63;

    float* dec = u;                       // [r*200+s]
    float* frT = u + 1600;                // [k*8+r]
    float* fiT = u + 1760;                // [k*8+r]
    float* part = u;                      // [(w*8+r)*64+d]

    // ---- P0: stage transposed fr/fi and ri
    if (tid < 2 * kR * kF) {              // first 256 of 320 entries
        int idx = tid;
        int tab = idx >= kR * kF; int j = idx - tab * kR * kF;
        u[1600 + idx] = (tab ? fi : fr)[(j & 7) * kF + (j >> 3)];
    }
    if (tid < 2 * kR * kF - 256) {        // remaining 64
        int idx = tid + 256;
        int j = idx - kR * kF;            // all in fi half
        u[1600 + idx] = fi[(j & 7) * kF + (j >> 3)];
    }
    {
        const float* tvb = tv + (size_t)bt * kR * kD;
        const float* tgb = target + (size_t)bt * kD;
        for (int idx = tid; idx < kR * kD; idx += 256)
            ri[idx] = (rel[idx] + tvb[idx]) * tgb[idx & 63];
    }
    __syncthreads();

    // ---- P1: decay + raw scores (thread = s)
    if (tid < kS) {
        const int s = tid;
        const bool valid = vm[b * kS + s] != 0;

        // decay: k-outer, 8 r-accumulators, transposed b128 broadcast reads
        {
            const float tt = dt[b * kS + s];
            float acc[kR];
#pragma unroll
            for (int r = 0; r < kR; ++r) acc[r] = 0.f;
#pragma unroll
            for (int k = 0; k < kF; ++k) {
                float w = 6.283185307179586f * ((float)k * (0.5f / (kF - 1))) * tt;
                float sn, cs; __sincosf(w, &sn, &cs);
                float4 f0 = *(const float4*)&frT[k * 8];
                float4 f1 = *(const float4*)&frT[k * 8 + 4];
                float4 g0 = *(const float4*)&fiT[k * 8];
                float4 g1 = *(const float4*)&fiT[k * 8 + 4];
                acc[0] += cs * f0.x - sn * g0.x;  acc[1] += cs * f0.y - sn * g0.y;
                acc[2] += cs * f0.z - sn * g0.z;  acc[3] += cs * f0.w - sn * g0.w;
                acc[4] += cs * f1.x - sn * g1.x;  acc[5] += cs * f1.y - sn * g1.y;
                acc[6] += cs * f1.z - sn * g1.z;  acc[7] += cs * f1.w - sn * g1.w;
            }
#pragma unroll
            for (int r = 0; r < kR; ++r) {
                float v = fminf(fmaxf(acc[r] * (1.0f / (2.0f * kF)), 0.f), 1.f);
                dec[r * kS + s] = valid ? v : 0.f;
            }
        }

        // raw scores
        {
            const float4* seqrow = (const float4*)(seq + (size_t)(b * kS + s) * kD);
            float a[kR];
#pragma unroll
            for (int r = 0; r < kR; ++r) a[r] = 0.f;
#pragma unroll
            for (int uu = 0; uu < kD / 4; ++uu) {
                float4 sv = seqrow[uu];
#pragma unroll
                for (int r = 0; r < kR; ++r) {
                    float4 rv = ((const float4*)(ri + r * kD))[uu];
                    a[r] += sv.x * rv.x + sv.y * rv.y + sv.z * rv.z + sv.w * rv.w;
                }
            }
#pragma unroll
            for (int r = 0; r < kR; ++r)
                att[r][s] = valid ? a[r] : -INFINITY;
        }
    }
    __syncthreads();

    // ---- P2: masked softmax * decay (wave w -> rows 2w, 2w+1)
#pragma unroll
    for (int h = 0; h < 2; ++h) {
        const int r = 2 * wave + h;
        float* row = &att[r][0];
        float a0 = row[lane];
        float a1 = row[lane + 64];
        float a2 = row[lane + 128];
        float a3 = (lane < kS - 192) ? row[lane + 192] : -INFINITY;
        float m = fmaxf(fmaxf(a0, a1), fmaxf(a2, a3));
#pragma unroll
        for (int off = 32; off; off >>= 1) m = fmaxf(m, __shfl_xor(m, off));
        float e0 = __expf(a0 - m), e1 = __expf(a1 - m), e2 = __expf(a2 - m);
        float e3 = (lane < kS - 192) ? __expf(a3 - m) : 0.f;
        float ssum = e0 + e1 + e2 + e3;
#pragma unroll
        for (int off = 32; off; off >>= 1) ssum += __shfl_xor(ssum, off);
        const float inv = 1.0f / ssum;
        row[lane]       = e0 * inv * dec[r * kS + lane];
        row[lane + 64]  = e1 * inv * dec[r * kS + lane + 64];
        row[lane + 128] = e2 * inv * dec[r * kS + lane + 128];
        if (lane < kS - 192)
            row[lane + 192] = e3 * inv * dec[r * kS + lane + 192];
    }
    __syncthreads();   // P3 reads all att rows; also fences dec -> part union

    // ---- P3: context partials; wave w takes s-groups g === w (mod 4)
    {
        float acc[kR];
#pragma unroll
        for (int r = 0; r < kR; ++r) acc[r] = 0.f;
        const float* seqb = seq + (size_t)b * kS * kD + lane;
        for (int g = wave; g < kS / 4; g += 4) {
            const int s0 = 4 * g;
            float4 av[kR];
#pragma unroll
            for (int r = 0; r < kR; ++r)
                av[r] = *(const float4*)&att[r][s0];
            float sv0 = seqb[(size_t)(s0 + 0) * kD];
            float sv1 = seqb[(size_t)(s0 + 1) * kD];
            float sv2 = seqb[(size_t)(s0 + 2) * kD];
            float sv3 = seqb[(size_t)(s0 + 3) * kD];
#pragma unroll
            for (int r = 0; r < kR; ++r)
                acc[r] += sv0 * av[r].x + sv1 * av[r].y + sv2 * av[r].z + sv3 * av[r].w;
        }
#pragma unroll
        for (int r = 0; r < kR; ++r)
            part[(wave * kR + r) * kD + lane] = acc[r];
    }
    __syncthreads();

    // ---- P4: reduce partials, coalesced store
    {
        int idx = tid;
#pragma unroll
        for (int it = 0; it < 2; ++it, idx += 256) {
            float v = part[idx] + part[512 + idx] + part[1024 + idx] + part[1536 + idx];
            out[(size_t)bt * kR * kD + idx] = v;
        }
    }
}

extern "C" void kernel_launch(void* const* d_in, const int* in_sizes, int n_in,
                              void* d_out, int out_size, void* d_ws, size_t ws_size,
                              hipStream_t stream) {
    const float* seq    = (const float*)d_in[0];
    const float* dt     = (const float*)d_in[1];
    const float* target = (const float*)d_in[2];
    const float* tv     = (const float*)d_in[3];
    const int*   vm     = (const int*)  d_in[4];
    const float* rel    = (const float*)d_in[5];
    const float* fr     = (const float*)d_in[6];
    const float* fi     = (const float*)d_in[7];
    float* out = (float*)d_out;

    rda_fused<<<kB * kT, 256, 0, stream>>>(seq, dt, target, tv, vm, rel, fr, fi, out);
}

// Round 7
// 105.920 us; speedup vs baseline: 2.8113x; 1.2459x over previous
//
#include <hip/hip_runtime.h>
#include <math.h>

// Problem constants (from reference)
constexpr int kB = 256, kT = 8, kS = 200, kR = 8, kD = 64, kF = 20;

// ---------------------------------------------------------------------------
// One block per (b,t), 256 threads = 4 waves, grid 2048.
// Block mapping: b = o%256, t = o/256  ->  o%8 == b%8, so all 8 t-blocks of a
// given b dispatch to the SAME XCD (o%8 round-robin): seq[b] (51 KB) is HBM-
// fetched once and L2-served 7x. Per-XCD seq footprint = 32 b's = 1.6MB < 4MB.
//
//   P0 : stage fr/fi transposed -> LDS; ri[r][d] = (rel+tv)*target -> LDS
//   P1 : thread s (<200): dec[r][s] via 20x __sincosf (k-outer, r-inner b128)
//        and att[r][s] = seq[b,s,:].ri[r,:]  (valid ? . : -inf)
//   P2 : wave w: softmax rows r=2w,2w+1 over s (shfl reduce), in place:
//        att[r][s] = e/denom * dec[r][s]
//   P3 : wave w owns s-groups g===w (mod 4): acc[r] += seq*att
//        (b128 broadcast along s), partials -> LDS
//   P4 : cross-wave reduce, coalesced store
// NOTES:
//  - global `att - att.max()` is shift-invariant under softmax -> omitted.
//  - decay concat halves identical: mean(2F)/2 == sum_F/(2F)  (== acc/40).
//  - d_ws deliberately unused: harness poison-fill of ws costs ~43us serial.
//  - LAUNCH BOUNDS: plain (256). Empirical gfx950 allocator rule from R5/R6:
//    arg w pins VGPR ~ 256/w -> (256,8)=32 VGPR/655MB spill, (256,4)=64/50MB
//    spill. This kernel's natural footprint is ~92 VGPR (R3, zero spill).
//    Never demand occupancy beyond the register footprint (G1/G6).
// ---------------------------------------------------------------------------
__global__ __launch_bounds__(256) void rda_fused(
    const float* __restrict__ seq,    // [B,S,D]
    const float* __restrict__ dt,     // [B,S]
    const float* __restrict__ target, // [B,T,D]
    const float* __restrict__ tv,     // [B,T,R,D]
    const int*   __restrict__ vm,     // [B,S]
    const float* __restrict__ rel,    // [R,D]
    const float* __restrict__ fr,     // [R,F]
    const float* __restrict__ fi,     // [R,F]
    float* __restrict__ out)          // [B,T,R,D]
{
    __shared__ float ri[kR * kD];        // 2 KB
    __shared__ float att[kR][kS];        // 6.4 KB, stride-1 rows (conflict-free)
    // union (time-disjoint, barrier-fenced):
    //   P1/P2: dec = u[0..1599] ([r][s]), ffT = u[1600..2239] (frT then fiT, [k][r])
    //   P3/P4: part = u[0..2047] ([w][r][d])
    __shared__ float u[2240];            // 8.96 KB

    const int o = blockIdx.x;
    const int b = o & 255, t = o >> 8;
    const int bt = b * kT + t;
    const int tid = threadIdx.x, wave = tid >> 6, lane = tid & 63;

    float* dec = u;                       // [r*200+s]
    float* frT = u + 1600;                // [k*8+r]
    float* fiT = u + 1760;                // [k*8+r]
    float* part = u;                      // [(w*8+r)*64+d]

    // ---- P0: stage transposed fr/fi and ri
    if (tid < 2 * kR * kF) {              // first 256 of 320 entries
        int idx = tid;
        int tab = idx >= kR * kF; int j = idx - tab * kR * kF;
        u[1600 + idx] = (tab ? fi : fr)[(j & 7) * kF + (j >> 3)];
    }
    if (tid < 2 * kR * kF - 256) {        // remaining 64
        int idx = tid + 256;
        int j = idx - kR * kF;            // all in fi half
        u[1600 + idx] = fi[(j & 7) * kF + (j >> 3)];
    }
    {
        const float* tvb = tv + (size_t)bt * kR * kD;
        const float* tgb = target + (size_t)bt * kD;
        for (int idx = tid; idx < kR * kD; idx += 256)
            ri[idx] = (rel[idx] + tvb[idx]) * tgb[idx & 63];
    }
    __syncthreads();

    // ---- P1: decay + raw scores (thread = s)
    if (tid < kS) {
        const int s = tid;
        const bool valid = vm[b * kS + s] != 0;

        // decay: k-outer, 8 r-accumulators, transposed b128 broadcast reads
        {
            const float tt = dt[b * kS + s];
            float acc[kR];
#pragma unroll
            for (int r = 0; r < kR; ++r) acc[r] = 0.f;
#pragma unroll
            for (int k = 0; k < kF; ++k) {
                float w = 6.283185307179586f * ((float)k * (0.5f / (kF - 1))) * tt;
                float sn, cs; __sincosf(w, &sn, &cs);
                float4 f0 = *(const float4*)&frT[k * 8];
                float4 f1 = *(const float4*)&frT[k * 8 + 4];
                float4 g0 = *(const float4*)&fiT[k * 8];
                float4 g1 = *(const float4*)&fiT[k * 8 + 4];
                acc[0] += cs * f0.x - sn * g0.x;  acc[1] += cs * f0.y - sn * g0.y;
                acc[2] += cs * f0.z - sn * g0.z;  acc[3] += cs * f0.w - sn * g0.w;
                acc[4] += cs * f1.x - sn * g1.x;  acc[5] += cs * f1.y - sn * g1.y;
                acc[6] += cs * f1.z - sn * g1.z;  acc[7] += cs * f1.w - sn * g1.w;
            }
#pragma unroll
            for (int r = 0; r < kR; ++r) {
                float v = fminf(fmaxf(acc[r] * (1.0f / (2.0f * kF)), 0.f), 1.f);
                dec[r * kS + s] = valid ? v : 0.f;
            }
        }

        // raw scores
        {
            const float4* seqrow = (const float4*)(seq + (size_t)(b * kS + s) * kD);
            float a[kR];
#pragma unroll
            for (int r = 0; r < kR; ++r) a[r] = 0.f;
#pragma unroll
            for (int uu = 0; uu < kD / 4; ++uu) {
                float4 sv = seqrow[uu];
#pragma unroll
                for (int r = 0; r < kR; ++r) {
                    float4 rv = ((const float4*)(ri + r * kD))[uu];
                    a[r] += sv.x * rv.x + sv.y * rv.y + sv.z * rv.z + sv.w * rv.w;
                }
            }
#pragma unroll
            for (int r = 0; r < kR; ++r)
                att[r][s] = valid ? a[r] : -INFINITY;
        }
    }
    __syncthreads();

    // ---- P2: masked softmax * decay (wave w -> rows 2w, 2w+1)
#pragma unroll
    for (int h = 0; h < 2; ++h) {
        const int r = 2 * wave + h;
        float* row = &att[r][0];
        float a0 = row[lane];
        float a1 = row[lane + 64];
        float a2 = row[lane + 128];
        float a3 = (lane < kS - 192) ? row[lane + 192] : -INFINITY;
        float m = fmaxf(fmaxf(a0, a1), fmaxf(a2, a3));
#pragma unroll
        for (int off = 32; off; off >>= 1) m = fmaxf(m, __shfl_xor(m, off));
        float e0 = __expf(a0 - m), e1 = __expf(a1 - m), e2 = __expf(a2 - m);
        float e3 = (lane < kS - 192) ? __expf(a3 - m) : 0.f;
        float ssum = e0 + e1 + e2 + e3;
#pragma unroll
        for (int off = 32; off; off >>= 1) ssum += __shfl_xor(ssum, off);
        const float inv = 1.0f / ssum;
        row[lane]       = e0 * inv * dec[r * kS + lane];
        row[lane + 64]  = e1 * inv * dec[r * kS + lane + 64];
        row[lane + 128] = e2 * inv * dec[r * kS + lane + 128];
        if (lane < kS - 192)
            row[lane + 192] = e3 * inv * dec[r * kS + lane + 192];
    }
    __syncthreads();   // P3 reads all att rows; also fences dec -> part union

    // ---- P3: context partials; wave w takes s-groups g === w (mod 4)
    {
        float acc[kR];
#pragma unroll
        for (int r = 0; r < kR; ++r) acc[r] = 0.f;
        const float* seqb = seq + (size_t)b * kS * kD + lane;
        for (int g = wave; g < kS / 4; g += 4) {
            const int s0 = 4 * g;
            float4 av[kR];
#pragma unroll
            for (int r = 0; r < kR; ++r)
                av[r] = *(const float4*)&att[r][s0];
            float sv0 = seqb[(size_t)(s0 + 0) * kD];
            float sv1 = seqb[(size_t)(s0 + 1) * kD];
            float sv2 = seqb[(size_t)(s0 + 2) * kD];
            float sv3 = seqb[(size_t)(s0 + 3) * kD];
#pragma unroll
            for (int r = 0; r < kR; ++r)
                acc[r] += sv0 * av[r].x + sv1 * av[r].y + sv2 * av[r].z + sv3 * av[r].w;
        }
#pragma unroll
        for (int r = 0; r < kR; ++r)
            part[(wave * kR + r) * kD + lane] = acc[r];
    }
    __syncthreads();

    // ---- P4: reduce partials, coalesced store
    {
        int idx = tid;
#pragma unroll
        for (int it = 0; it < 2; ++it, idx += 256) {
            float v = part[idx] + part[512 + idx] + part[1024 + idx] + part[1536 + idx];
            out[(size_t)bt * kR * kD + idx] = v;
        }
    }
}

extern "C" void kernel_launch(void* const* d_in, const int* in_sizes, int n_in,
                              void* d_out, int out_size, void* d_ws, size_t ws_size,
                              hipStream_t stream) {
    const float* seq    = (const float*)d_in[0];
    const float* dt     = (const float*)d_in[1];
    const float* target = (const float*)d_in[2];
    const float* tv     = (const float*)d_in[3];
    const int*   vm     = (const int*)  d_in[4];
    const float* rel    = (const float*)d_in[5];
    const float* fr     = (const float*)d_in[6];
    const float* fi     = (const float*)d_in[7];
    float* out = (float*)d_out;

    rda_fused<<<kB * kT, 256, 0, stream>>>(seq, dt, target, tv, vm, rel, fr, fi, out);
}